// Round 1
// baseline (188.308 us; speedup 1.0000x reference)
//
#include <hip/hip_runtime.h>

typedef unsigned short u16;
typedef __attribute__((ext_vector_type(4))) float f32x4;
typedef __attribute__((ext_vector_type(8))) short short8;

#define AS1 __attribute__((address_space(1)))
#define AS3 __attribute__((address_space(3)))

#define B_  2
#define T_  2048
#define C_  1024
#define H_  16
#define HD_ 64
#define N3C 3072
#define BT_ 4096

__device__ __forceinline__ u16 f2bf(float x) {
    unsigned u = __float_as_uint(x);
    u += 0x7fff + ((u >> 16) & 1);          // RTNE
    return (u16)(u >> 16);
}

// one-instruction packed fp32x2 -> bf16x2 (RTNE), gfx950
__device__ __forceinline__ unsigned cvt_pk_bf16(float a, float b) {
    unsigned r;
    asm("v_cvt_pk_bf16_f32 %0, %1, %2" : "=v"(r) : "v"(a), "v"(b));
    return r;
}

// ---------------------------------------------------------------------------
// Fused conversion kernel: blocks [0,4096) = x fp32->bf16;
// [4096,4864) = Wqkv transpose; [4864,5120) = Wproj transpose.
// ---------------------------------------------------------------------------
__global__ __launch_bounds__(256)
void conv_all(const float* __restrict__ x, u16* __restrict__ xb,
              const float* __restrict__ Wq, u16* __restrict__ WqT,
              const float* __restrict__ Wp, u16* __restrict__ WpT) {
    __shared__ float tile[64][68];
    const int tid = threadIdx.x;
    const int b = blockIdx.x;
    if (b < 4096) {
        int i = b * 256 + tid;
        float4 f = ((const float4*)x)[i];
        uint2 o;
        o.x = cvt_pk_bf16(f.x, f.y);
        o.y = cvt_pk_bf16(f.z, f.w);
        ((uint2*)xb)[i] = o;
        return;
    }
    const float* W; u16* WT; int N, k0, n0;
    if (b < 4096 + 768) {
        int bb = b - 4096; W = Wq; WT = WqT; N = N3C;
        n0 = (bb % 48) * 64; k0 = (bb / 48) * 64;
    } else {
        int bb = b - 4864; W = Wp; WT = WpT; N = C_;
        n0 = (bb % 16) * 64; k0 = (bb / 16) * 64;
    }
    #pragma unroll
    for (int i = 0; i < 4; ++i) {
        int slot = tid + i * 256;
        int row = slot >> 4, c4 = (slot & 15) * 4;
        *(float4*)&tile[row][c4] = *(const float4*)&W[(size_t)(k0 + row) * N + n0 + c4];
    }
    __syncthreads();
    #pragma unroll
    for (int i = 0; i < 4; ++i) {
        int slot = tid + i * 256;
        int nn = slot >> 4, k4 = (slot & 15) * 4;
        uint2 o;
        o.x = cvt_pk_bf16(tile[k4 + 0][nn], tile[k4 + 1][nn]);
        o.y = cvt_pk_bf16(tile[k4 + 2][nn], tile[k4 + 3][nn]);
        *(uint2*)&WT[(size_t)(n0 + nn) * 1024 + k0 + k4] = o;
    }
}

// ---------------------------------------------------------------------------
// QKV GEMM, 256x256 tile / 8 waves / BK=32 ring-4 phased schedule.
// Per K-tile: 2 phases x 16 MFMA; each phase issues 2 global_load_lds for
// tile t+3 (ring depth 4 => boundary wait is vmcnt(8), never 0).
// LDS 128 KB (4 slots x 256x32 x bf16 x {A,B}).  q pre-scaled by
// 1/8*log2(e); outputs q,k -> [B,H,T,HD], v -> [B,H,HD,T].
// ---------------------------------------------------------------------------
__global__ __launch_bounds__(512, 2)
void qkv_gemm(const u16* __restrict__ A, const u16* __restrict__ BT,
              const float* __restrict__ bias,
              u16* __restrict__ q, u16* __restrict__ k, u16* __restrict__ vT) {
    __shared__ __align__(16) u16 As[4][256 * 32];
    __shared__ __align__(16) u16 Bs[4][256 * 32];
    const int tid  = threadIdx.x;
    const int lane = tid & 63, w = tid >> 6;          // 8 waves
    const int wr = w >> 2, wc = w & 3;                // 2M x 4N wave grid
    const int l15 = lane & 15, quad = lane >> 4;

    // bijective XCD swizzle: 192 blocks, 24/XCD; XCD x owns M-panels {2x,2x+1}
    const int bid = blockIdx.x;
    const int bm = ((bid & 7) << 1) | ((bid >> 3) & 1);   // [0,16)
    const int bn = bid >> 4;                              // [0,12)
    const int m0 = bm * 256, n0 = bn * 256;

    // staging: lane -> row lane>>2, chunk lane&3; source pre-swizzled by
    // f(row) = (row&3) ^ ((row>>2)&3)  (== ((lane>>2)&3) ^ (lane>>4) here)
    const int srow4 = lane >> 2;
    const int gch   = ((lane & 3) ^ ((lane >> 2) & 3) ^ (lane >> 4)) * 8;
    const int fl    = (l15 & 3) ^ (l15 >> 2);             // f(row) on read side

    const u16* gA = A  + (size_t)(m0 + w * 16 + srow4) * 1024 + gch;
    const u16* gB = BT + (size_t)(n0 + w * 16 + srow4) * 1024 + gch;

    auto stageA = [&](int t) {
        const int sl = t & 3;
        #pragma unroll
        for (int j = 0; j < 2; ++j)
            __builtin_amdgcn_global_load_lds(
                (const AS1 void*)(gA + (size_t)j * 128 * 1024 + t * 32),
                (AS3 void*)(&As[sl][(j * 128 + w * 16) * 32]), 16, 0, 0);
    };
    auto stageB = [&](int t) {
        const int sl = t & 3;
        #pragma unroll
        for (int j = 0; j < 2; ++j)
            __builtin_amdgcn_global_load_lds(
                (const AS1 void*)(gB + (size_t)j * 128 * 1024 + t * 32),
                (AS3 void*)(&Bs[sl][(j * 128 + w * 16) * 32]), 16, 0, 0);
    };

    f32x4 acc[8][4] = {};

    // prologue: stage tiles 0,1,2 (12 loads); wait tile 0 (4 oldest) landed
    stageA(0); stageB(0); stageA(1); stageB(1); stageA(2); stageB(2);
    asm volatile("s_waitcnt vmcnt(8)\n\ts_barrier" ::: "memory");

    const int aoff = (wr * 128 + l15) * 32 + (quad ^ fl) * 8;
    const int boff = (wc * 64  + l15) * 32 + (quad ^ fl) * 8;

    auto tile_body = [&](int t, bool doStage) {
        const u16* Ac = &As[t & 3][0];
        const u16* Bc = &Bs[t & 3][0];
        short8 a[8], b[4];
        // ---- phase 0: mf 0-3 x nf 0-3 ----
        #pragma unroll
        for (int mf = 0; mf < 4; ++mf)
            a[mf] = *(const short8*)&Ac[aoff + mf * 512];
        #pragma unroll
        for (int nf = 0; nf < 4; ++nf)
            b[nf] = *(const short8*)&Bc[boff + nf * 512];
        if (doStage) stageA(t + 3);
        asm volatile("s_barrier\n\ts_waitcnt lgkmcnt(0)" ::: "memory");
        __builtin_amdgcn_s_setprio(1);
        #pragma unroll
        for (int mf = 0; mf < 4; ++mf)
            #pragma unroll
            for (int nf = 0; nf < 4; ++nf)
                acc[mf][nf] = __builtin_amdgcn_mfma_f32_16x16x32_bf16(a[mf], b[nf], acc[mf][nf], 0, 0, 0);
        __builtin_amdgcn_s_setprio(0);
        asm volatile("s_barrier" ::: "memory");
        // ---- phase 1: mf 4-7 x nf 0-3 (b reused in regs) ----
        #pragma unroll
        for (int mf = 0; mf < 4; ++mf)
            a[4 + mf] = *(const short8*)&Ac[aoff + (4 + mf) * 512];
        if (doStage) stageB(t + 3);
        asm volatile("s_barrier\n\ts_waitcnt lgkmcnt(0)" ::: "memory");
        __builtin_amdgcn_s_setprio(1);
        #pragma unroll
        for (int mf = 0; mf < 4; ++mf)
            #pragma unroll
            for (int nf = 0; nf < 4; ++nf)
                acc[4 + mf][nf] = __builtin_amdgcn_mfma_f32_16x16x32_bf16(a[4 + mf], b[nf], acc[4 + mf][nf], 0, 0, 0);
        __builtin_amdgcn_s_setprio(0);
        // tile-end vmcnt+barrier supplied by caller
    };

    #pragma unroll 1
    for (int t = 0; t < 29; ++t) {
        tile_body(t, true);
        // tiles t+2,t+3 (8 loads) stay in flight; tile t+1 guaranteed landed
        asm volatile("s_waitcnt vmcnt(8)\n\ts_barrier" ::: "memory");
    }
    tile_body(29, false);
    asm volatile("s_waitcnt vmcnt(4)\n\ts_barrier" ::: "memory");
    tile_body(30, false);
    asm volatile("s_waitcnt vmcnt(0)\n\ts_barrier" ::: "memory");
    tile_body(31, false);

    // ---- epilogue: bias + scatter (q scaled for exp2 attention) ----
    const int which = n0 >> 10;
    const float QSCALE = 0.125f * 1.4426950408889634f;   // 1/8 * log2(e)
    #pragma unroll
    for (int nf = 0; nf < 4; ++nf) {
        const int n = n0 + wc * 64 + nf * 16 + l15;
        const int nl = n & 1023, h = nl >> 6, d = nl & 63;
        const float bv = bias[n];
        #pragma unroll
        for (int mf = 0; mf < 8; ++mf) {
            const int mb = m0 + wr * 128 + mf * 16 + quad * 4;
            const int bb = mb >> 11, t0 = mb & 2047;
            f32x4 v4 = acc[mf][nf];
            if (which == 0) {
                size_t base = ((size_t)(bb * H_ + h) * T_ + t0) * HD_ + d;
                #pragma unroll
                for (int r = 0; r < 4; ++r)
                    q[base + (size_t)r * HD_] = f2bf((v4[r] + bv) * QSCALE);
            } else if (which == 1) {
                size_t base = ((size_t)(bb * H_ + h) * T_ + t0) * HD_ + d;
                #pragma unroll
                for (int r = 0; r < 4; ++r)
                    k[base + (size_t)r * HD_] = f2bf(v4[r] + bv);
            } else {
                uint2 o;
                o.x = cvt_pk_bf16(v4[0] + bv, v4[1] + bv);
                o.y = cvt_pk_bf16(v4[2] + bv, v4[3] + bv);
                *(uint2*)&vT[((size_t)(bb * H_ + h) * HD_ + d) * T_ + t0] = o;
            }
        }
    }
}

// ---------------------------------------------------------------------------
// Flash attention v7 = R8 work distribution + R9 LDS diet:
// one 64-row q-tile per block (1024 blocks, heavy first -> dynamic backfill,
// ALL 4 waves active every phase; 16.9k total block-phases).  LDS = K/V dbuf
// only (32 KB); P written into the DEAD half of Ks[cur] (K/V frags already in
// regs, enforced by mid lgkm+barrier).  2 barriers/phase.  S^T = K.Q^T,
// unnormalized exp2 (log2e folded into q upstream).
// ---------------------------------------------------------------------------
__global__ __launch_bounds__(256, 4)
void attn(const u16* __restrict__ q, const u16* __restrict__ k,
          const u16* __restrict__ vT, u16* __restrict__ y) {
    __shared__ __align__(16) u16 Ks[2 * 64 * 64];
    __shared__ __align__(16) u16 Vs[2 * 64 * 64];
    const int tid = threadIdx.x;
    const int lane = tid & 63, w = tid >> 6;
    const int l15 = lane & 15, quad = lane >> 4;
    const int srow = lane >> 3, schunk = (lane & 7) ^ srow;
    const int idx = blockIdx.x;
    const int bh = idx & 31;                        // bh%8 = XCD locality
    const int qt = 31 - (idx >> 5);                 // heavy first
    const u16* qp = q  + (size_t)bh * T_ * HD_;
    const u16* kp = k  + (size_t)bh * T_ * HD_;
    const u16* vp = vT + (size_t)bh * HD_ * T_;

    const int qrow = qt * 64 + w * 16 + l15;
    short8 qf[2];
    #pragma unroll
    for (int s = 0; s < 2; ++s)
        qf[s] = *(const short8*)&qp[(size_t)qrow * HD_ + s * 32 + quad * 8];

    auto stage = [&](int buf, int kt) {
        const int kb = kt * 64;
        // wave-local fence: previous phase's P reads (same rows, other buffer
        // half) must retire before the DMA write can be issued/hoisted here.
        asm volatile("s_waitcnt lgkmcnt(0)" ::: "memory");
        #pragma unroll
        for (int j = 0; j < 2; ++j) {
            int row = w * 16 + j * 8 + srow;
            __builtin_amdgcn_global_load_lds(
                (const AS1 void*)(kp + (size_t)(kb + row) * HD_ + schunk * 8),
                (AS3 void*)(Ks + buf * (64 * 64) + (w * 16 + j * 8) * 64), 16, 0, 0);
            __builtin_amdgcn_global_load_lds(
                (const AS1 void*)(vp + (size_t)row * T_ + kb + schunk * 8),
                (AS3 void*)(Vs + buf * (64 * 64) + (w * 16 + j * 8) * 64), 16, 0, 0);
        }
    };

    f32x4 o[4] = {};
    float l = 0.f;
    stage(0, 0);

    for (int kt = 0; kt <= qt; ++kt) {
        const int kb = kt * 64;
        const int cur = kt & 1;
        if (kt < qt) {
            stage(cur ^ 1, kt + 1);
            asm volatile("s_waitcnt vmcnt(4)\n\ts_barrier" ::: "memory");
        } else {
            asm volatile("s_waitcnt vmcnt(0)\n\ts_barrier" ::: "memory");
        }
        u16* Kc = Ks + cur * (64 * 64);
        const u16* Vc = Vs + cur * (64 * 64);

        short8 ka[4][2], va[4][2];
        #pragma unroll
        for (int ct = 0; ct < 4; ++ct)
            #pragma unroll
            for (int s = 0; s < 2; ++s) {
                int xo = ((s * 4 + quad) ^ (l15 & 7)) * 8;
                ka[ct][s] = *(const short8*)&Kc[(ct * 16 + l15) * 64 + xo];
                va[ct][s] = *(const short8*)&Vc[(ct * 16 + l15) * 64 + xo];
            }
        // all waves' K/V fragment reads complete before P overwrites Ks[cur]
        asm volatile("s_waitcnt lgkmcnt(0)\n\ts_barrier" ::: "memory");

        // S^T = K.Q^T  (C row = key, col = q = l15);  scores already *log2e
        f32x4 st[4] = {};
        #pragma unroll
        for (int s = 0; s < 2; ++s)
            #pragma unroll
            for (int ct = 0; ct < 4; ++ct)
                st[ct] = __builtin_amdgcn_mfma_f32_16x16x32_bf16(ka[ct][s], qf[s], st[ct], 0, 0, 0);

        float pe[16];
        #pragma unroll
        for (int ct = 0; ct < 4; ++ct)
            #pragma unroll
            for (int r = 0; r < 4; ++r)
                pe[ct * 4 + r] = exp2f(st[ct][r]);
        if (kt == qt) {                              // wave-uniform causal mask
            #pragma unroll
            for (int ct = 0; ct < 4; ++ct)
                #pragma unroll
                for (int r = 0; r < 4; ++r)
                    if ((kb + ct * 16 + quad * 4 + r) > qrow) pe[ct * 4 + r] = 0.f;
        }
        float psum = 0.f;
        #pragma unroll
        for (int i = 0; i < 16; ++i) psum += pe[i];
        l += psum;

        // P -> dead Ks[cur], wave-own rows w*16.., stride 64, XOR chunks
        u16* Pw = Kc + (w * 16 + l15) * 64;
        #pragma unroll
        for (int ct = 0; ct < 4; ++ct) {
            int chunk = ct * 2 + (quad >> 1);
            int off = ((chunk ^ (l15 & 7)) << 3) + (quad & 1) * 4;
            uint2 pk;
            pk.x = cvt_pk_bf16(pe[ct * 4 + 0], pe[ct * 4 + 1]);
            pk.y = cvt_pk_bf16(pe[ct * 4 + 2], pe[ct * 4 + 3]);
            *(uint2*)&Pw[off] = pk;
        }
        asm volatile("s_waitcnt lgkmcnt(0)" ::: "memory");   // wave-local RT

        // O^T = V^T . P^T
        #pragma unroll
        for (int s = 0; s < 2; ++s) {
            short8 pb = *(const short8*)&Pw[(((s * 4 + quad) ^ (l15 & 7)) << 3)];
            #pragma unroll
            for (int n = 0; n < 4; ++n)
                o[n] = __builtin_amdgcn_mfma_f32_16x16x32_bf16(va[n][s], pb, o[n], 0, 0, 0);
        }
        // no end barrier: P rows are wave-private; cross-wave safety is the
        // mid lgkm+barrier, buffer reuse safety is the top vmcnt+barrier.
    }

    l += __shfl_xor(l, 16); l += __shfl_xor(l, 32);
    const float inv = 1.f / l;
    const int bb = bh >> 4, h = bh & 15;
    #pragma unroll
    for (int n = 0; n < 4; ++n) {
        uint2 pk;
        pk.x = cvt_pk_bf16(o[n][0] * inv, o[n][1] * inv);
        pk.y = cvt_pk_bf16(o[n][2] * inv, o[n][3] * inv);
        *(uint2*)&y[((size_t)(bb * T_ + qrow)) * C_ + h * 64 + n * 16 + quad * 4] = pk;
    }
}

// ---------------------------------------------------------------------------
// Output projection: y[4096][1024] @ WprojT[1024][1024]^T + bias -> fp32 out.
// 128x64 tile (512 blocks, 48 KB LDS -> 3 blocks/CU).
// ---------------------------------------------------------------------------
__global__ __launch_bounds__(256, 3)
void proj_gemm(const u16* __restrict__ A, const u16* __restrict__ BT,
               const float* __restrict__ bias, float* __restrict__ out) {
    __shared__ __align__(16) u16 As[2 * 128 * 64];
    __shared__ __align__(16) u16 Bs[2 * 64 * 64];
    const int m0 = blockIdx.y * 128, n0 = blockIdx.x * 64;
    const int tid = threadIdx.x;
    const int lane = tid & 63, w = tid >> 6;
    const int l15 = lane & 15, quad = lane >> 4;
    const int row0 = (w & 1) * 64, col0 = (w >> 1) * 32;
    const int srow = lane >> 3;
    const int schunk = (lane & 7) ^ srow;
    f32x4 acc[4][2] = {};

    auto stage = [&](int buf, int k0) {
        #pragma unroll
        for (int j = 0; j < 4; ++j) {
            int rbase = w * 32 + j * 8;
            const u16* ga = A + (size_t)(m0 + rbase + srow) * 1024 + k0 + schunk * 8;
            __builtin_amdgcn_global_load_lds((const AS1 void*)ga,
                (AS3 void*)(As + buf * (128 * 64) + rbase * 64), 16, 0, 0);
        }
        #pragma unroll
        for (int j = 0; j < 2; ++j) {
            int rbase = w * 16 + j * 8;
            const u16* gb = BT + (size_t)(n0 + rbase + srow) * 1024 + k0 + schunk * 8;
            __builtin_amdgcn_global_load_lds((const AS1 void*)gb,
                (AS3 void*)(Bs + buf * (64 * 64) + rbase * 64), 16, 0, 0);
        }
    };

    stage(0, 0);
    #pragma unroll
    for (int it = 0; it < 16; ++it) {
        const int cur = it & 1;
        if (it + 1 < 16) {
            stage(cur ^ 1, (it + 1) * 64);
            asm volatile("s_waitcnt vmcnt(6)\n\ts_barrier" ::: "memory");
        } else {
            asm volatile("s_waitcnt vmcnt(0)\n\ts_barrier" ::: "memory");
        }
        const u16* Ac = As + cur * (128 * 64);
        const u16* Bc = Bs + cur * (64 * 64);
        #pragma unroll
        for (int s = 0; s < 2; ++s) {
            short8 a[4], b[2];
            #pragma unroll
            for (int rt = 0; rt < 4; ++rt) {
                int row = row0 + rt * 16 + l15;
                a[rt] = *(const short8*)&Ac[row * 64 + (((s * 4 + quad) ^ (l15 & 7)) * 8)];
            }
            #pragma unroll
            for (int ct = 0; ct < 2; ++ct) {
                int row = col0 + ct * 16 + l15;
                b[ct] = *(const short8*)&Bc[row * 64 + (((s * 4 + quad) ^ (l15 & 7)) * 8)];
            }
            #pragma unroll
            for (int rt = 0; rt < 4; ++rt)
                #pragma unroll
                for (int ct = 0; ct < 2; ++ct)
                    acc[rt][ct] = __builtin_amdgcn_mfma_f32_16x16x32_bf16(a[rt], b[ct], acc[rt][ct], 0, 0, 0);
        }
        asm volatile("s_waitcnt lgkmcnt(0)\n\ts_barrier" ::: "memory");
    }

    #pragma unroll
    for (int ct = 0; ct < 2; ++ct) {
        int n = n0 + col0 + ct * 16 + l15;
        float bv = bias[n];
        #pragma unroll
        for (int rt = 0; rt < 4; ++rt) {
            int mb = m0 + row0 + rt * 16 + quad * 4;
            f32x4 v4 = acc[rt][ct];
            #pragma unroll
            for (int r = 0; r < 4; ++r)
                out[(size_t)(mb + r) * 1024 + n] = v4[r] + bv;
        }
    }
}

// ---------------------------------------------------------------------------
extern "C" void kernel_launch(void* const* d_in, const int* in_sizes, int n_in,
                              void* d_out, int out_size, void* d_ws, size_t ws_size,
                              hipStream_t stream) {
    const float* x     = (const float*)d_in[0];
    const float* Wqkv  = (const float*)d_in[1];
    const float* bqkv  = (const float*)d_in[2];
    const float* Wproj = (const float*)d_in[3];
    const float* bproj = (const float*)d_in[4];

    u16* xb     = (u16*)d_ws;
    u16* WqkvT  = xb + (size_t)4 * 1024 * 1024;
    u16* WprojT = WqkvT + (size_t)3 * 1024 * 1024;
    u16* q      = WprojT + (size_t)1024 * 1024;
    u16* kk     = q + (size_t)4 * 1024 * 1024;
    u16* vT     = kk + (size_t)4 * 1024 * 1024;
    u16* y      = vT + (size_t)4 * 1024 * 1024;

    conv_all<<<5120, 256, 0, stream>>>(x, xb, Wqkv, WqkvT, Wproj, WprojT);
    qkv_gemm<<<192, 512, 0, stream>>>(xb, WqkvT, bqkv, q, kk, vT);
    attn<<<1024, 256, 0, stream>>>(q, kk, vT, y);
    proj_gemm<<<dim3(C_ / 64, BT_ / 128), 256, 0, stream>>>(y, WprojT, bproj, (float*)d_out);
}

// Round 2
// 173.672 us; speedup vs baseline: 1.0843x; 1.0843x over previous
//
#include <hip/hip_runtime.h>

typedef unsigned short u16;
typedef __attribute__((ext_vector_type(4))) float f32x4;
typedef __attribute__((ext_vector_type(8))) short short8;

#define AS1 __attribute__((address_space(1)))
#define AS3 __attribute__((address_space(3)))

#define B_  2
#define T_  2048
#define C_  1024
#define H_  16
#define HD_ 64
#define N3C 3072
#define BT_ 4096

__device__ __forceinline__ u16 f2bf(float x) {
    unsigned u = __float_as_uint(x);
    u += 0x7fff + ((u >> 16) & 1);          // RTNE
    return (u16)(u >> 16);
}

// one-instruction packed fp32x2 -> bf16x2 (RTNE), gfx950
__device__ __forceinline__ unsigned cvt_pk_bf16(float a, float b) {
    unsigned r;
    asm("v_cvt_pk_bf16_f32 %0, %1, %2" : "=v"(r) : "v"(a), "v"(b));
    return r;
}

// ---------------------------------------------------------------------------
// Fused conversion kernel: blocks [0,4096) = x fp32->bf16;
// [4096,4864) = Wqkv transpose; [4864,5120) = Wproj transpose.
// ---------------------------------------------------------------------------
__global__ __launch_bounds__(256)
void conv_all(const float* __restrict__ x, u16* __restrict__ xb,
              const float* __restrict__ Wq, u16* __restrict__ WqT,
              const float* __restrict__ Wp, u16* __restrict__ WpT) {
    __shared__ float tile[64][68];
    const int tid = threadIdx.x;
    const int b = blockIdx.x;
    if (b < 4096) {
        int i = b * 256 + tid;
        float4 f = ((const float4*)x)[i];
        uint2 o;
        o.x = cvt_pk_bf16(f.x, f.y);
        o.y = cvt_pk_bf16(f.z, f.w);
        ((uint2*)xb)[i] = o;
        return;
    }
    const float* W; u16* WT; int N, k0, n0;
    if (b < 4096 + 768) {
        int bb = b - 4096; W = Wq; WT = WqT; N = N3C;
        n0 = (bb % 48) * 64; k0 = (bb / 48) * 64;
    } else {
        int bb = b - 4864; W = Wp; WT = WpT; N = C_;
        n0 = (bb % 16) * 64; k0 = (bb / 16) * 64;
    }
    #pragma unroll
    for (int i = 0; i < 4; ++i) {
        int slot = tid + i * 256;
        int row = slot >> 4, c4 = (slot & 15) * 4;
        *(float4*)&tile[row][c4] = *(const float4*)&W[(size_t)(k0 + row) * N + n0 + c4];
    }
    __syncthreads();
    #pragma unroll
    for (int i = 0; i < 4; ++i) {
        int slot = tid + i * 256;
        int nn = slot >> 4, k4 = (slot & 15) * 4;
        uint2 o;
        o.x = cvt_pk_bf16(tile[k4 + 0][nn], tile[k4 + 1][nn]);
        o.y = cvt_pk_bf16(tile[k4 + 2][nn], tile[k4 + 3][nn]);
        *(uint2*)&WT[(size_t)(n0 + nn) * 1024 + k0 + k4] = o;
    }
}

// ---------------------------------------------------------------------------
// QKV GEMM, 256(M)x192(N) tile / 8 waves / BK=64, 4 phases x 12 MFMA per
// K-tile, dbuf-2 LDS with counted vmcnt (never 0 in steady state).
// Proven 0-conflict LDS swizzle: 128B rows, chunk=(lane&7)^srow on write
// (pre-swizzled global source), chunk=((s*4+quad)^(l15&7)) on read.
// Per-wave load order for tile t+1: [B0,B1,B2, Aq0,Aq2, Aq1,Aq3] spread
// ph0:{B0,B1} ph1:{B2,Aq0} ph2:{Aq2} ph3:{Aq1,Aq3}; residency waits:
// vmcnt(2) at ph0-end (drains A-odd quarters of t) and ph3-end (drains
// B + A-even of t+1).  LDS 112 KB -> 1 block/CU, 2 waves/SIMD.
// Grid 256 = full chip; bijective XCD swizzle (XCD owns 2 M-panels).
// q pre-scaled by 1/8*log2(e); q,k -> [B,H,T,HD], v -> [B,H,HD,T].
// ---------------------------------------------------------------------------
__global__ __launch_bounds__(512, 2)
void qkv_gemm(const u16* __restrict__ A, const u16* __restrict__ BT,
              const float* __restrict__ bias,
              u16* __restrict__ q, u16* __restrict__ k, u16* __restrict__ vT) {
    __shared__ __align__(16) u16 As[2][256 * 64];
    __shared__ __align__(16) u16 Bs[2][192 * 64];
    const int tid  = threadIdx.x;
    const int lane = tid & 63, w = tid >> 6;          // 8 waves
    const int wr = w >> 2, wc = w & 3;                // 2M x 4N wave grid
    const int l15 = lane & 15, quad = lane >> 4;
    const int srow = lane >> 3, schunk = (lane & 7) ^ srow;

    // bijective XCD swizzle: 256 blocks, 32/XCD; XCD x owns M-panels {2x,2x+1}
    const int bid = blockIdx.x;
    const int xcd = bid & 7, rr = bid >> 3;           // rr in [0,32)
    const int bm = (xcd << 1) | (rr & 1);             // [0,16)
    const int bn = rr >> 1;                           // [0,16)
    const int m0 = bm * 256, n0 = bn * 192;

    // per-wave global staging bases (pre-swizzled source, linear LDS dest)
    const u16* gA = A  + (size_t)(m0 + w * 8  + srow) * 1024 + schunk * 8;
    const u16* gB = BT + (size_t)(n0 + w * 24 + srow) * 1024 + schunk * 8;

    auto stA = [&](int t, int qq) {   // 8 rows at w*8 + qq*64
        __builtin_amdgcn_global_load_lds(
            (const AS1 void*)(gA + (size_t)qq * 64 * 1024 + t * 64),
            (AS3 void*)(&As[t & 1][(w * 8 + qq * 64) * 64]), 16, 0, 0);
    };
    auto stB = [&](int t, int g) {    // 8 rows at w*24 + g*8
        __builtin_amdgcn_global_load_lds(
            (const AS1 void*)(gB + (size_t)g * 8 * 1024 + t * 64),
            (AS3 void*)(&Bs[t & 1][(w * 24 + g * 8) * 64]), 16, 0, 0);
    };

    f32x4 acc[8][3] = {};

    // prologue: tile 0 in order B0,B1,B2,Aq0,Aq2,Aq1,Aq3 -> steady-state wait
    stB(0, 0); stB(0, 1); stB(0, 2); stA(0, 0); stA(0, 2); stA(0, 1); stA(0, 3);
    asm volatile("s_waitcnt vmcnt(2)\n\ts_barrier" ::: "memory");

    #pragma unroll 1
    for (int t = 0; t < 16; ++t) {
        const u16* Ac = &As[t & 1][0];
        const u16* Bc = &Bs[t & 1][0];
        const bool st = (t < 15);
        short8 a[4], b[3];

        // ---- ph0: s=0, mf 0-3 (needs B all + A even quarters) ----
        {
            const int xo = (quad ^ (l15 & 7)) * 8;
            #pragma unroll
            for (int mf = 0; mf < 4; ++mf)
                a[mf] = *(const short8*)&Ac[(wr * 128 + mf * 16 + l15) * 64 + xo];
            #pragma unroll
            for (int nf = 0; nf < 3; ++nf)
                b[nf] = *(const short8*)&Bc[(wc * 48 + nf * 16 + l15) * 64 + xo];
            if (st) { stB(t + 1, 0); stB(t + 1, 1); }
            asm volatile("s_barrier\n\ts_waitcnt lgkmcnt(0)" ::: "memory");
            __builtin_amdgcn_s_setprio(1);
            #pragma unroll
            for (int mf = 0; mf < 4; ++mf)
                #pragma unroll
                for (int nf = 0; nf < 3; ++nf)
                    acc[mf][nf] = __builtin_amdgcn_mfma_f32_16x16x32_bf16(a[mf], b[nf], acc[mf][nf], 0, 0, 0);
            __builtin_amdgcn_s_setprio(0);
            // drain this tile's A-odd quarters (oldest in flight) before ph1
            if (st) asm volatile("s_waitcnt vmcnt(2)\n\ts_barrier" ::: "memory");
            else    asm volatile("s_waitcnt vmcnt(0)\n\ts_barrier" ::: "memory");
        }
        // ---- ph1: s=0, mf 4-7 (b reused in regs) ----
        {
            const int xo = (quad ^ (l15 & 7)) * 8;
            #pragma unroll
            for (int mf = 0; mf < 4; ++mf)
                a[mf] = *(const short8*)&Ac[(wr * 128 + (4 + mf) * 16 + l15) * 64 + xo];
            if (st) { stB(t + 1, 2); stA(t + 1, 0); }
            asm volatile("s_barrier\n\ts_waitcnt lgkmcnt(0)" ::: "memory");
            __builtin_amdgcn_s_setprio(1);
            #pragma unroll
            for (int mf = 0; mf < 4; ++mf)
                #pragma unroll
                for (int nf = 0; nf < 3; ++nf)
                    acc[4 + mf][nf] = __builtin_amdgcn_mfma_f32_16x16x32_bf16(a[mf], b[nf], acc[4 + mf][nf], 0, 0, 0);
            __builtin_amdgcn_s_setprio(0);
            asm volatile("s_barrier" ::: "memory");
        }
        // ---- ph2: s=1, mf 0-3 (+ b s=1) ----
        {
            const int xo = ((4 + quad) ^ (l15 & 7)) * 8;
            #pragma unroll
            for (int mf = 0; mf < 4; ++mf)
                a[mf] = *(const short8*)&Ac[(wr * 128 + mf * 16 + l15) * 64 + xo];
            #pragma unroll
            for (int nf = 0; nf < 3; ++nf)
                b[nf] = *(const short8*)&Bc[(wc * 48 + nf * 16 + l15) * 64 + xo];
            if (st) stA(t + 1, 2);
            asm volatile("s_barrier\n\ts_waitcnt lgkmcnt(0)" ::: "memory");
            __builtin_amdgcn_s_setprio(1);
            #pragma unroll
            for (int mf = 0; mf < 4; ++mf)
                #pragma unroll
                for (int nf = 0; nf < 3; ++nf)
                    acc[mf][nf] = __builtin_amdgcn_mfma_f32_16x16x32_bf16(a[mf], b[nf], acc[mf][nf], 0, 0, 0);
            __builtin_amdgcn_s_setprio(0);
            asm volatile("s_barrier" ::: "memory");
        }
        // ---- ph3: s=1, mf 4-7 ----
        {
            const int xo = ((4 + quad) ^ (l15 & 7)) * 8;
            #pragma unroll
            for (int mf = 0; mf < 4; ++mf)
                a[mf] = *(const short8*)&Ac[(wr * 128 + (4 + mf) * 16 + l15) * 64 + xo];
            if (st) { stA(t + 1, 1); stA(t + 1, 3); }
            asm volatile("s_barrier\n\ts_waitcnt lgkmcnt(0)" ::: "memory");
            __builtin_amdgcn_s_setprio(1);
            #pragma unroll
            for (int mf = 0; mf < 4; ++mf)
                #pragma unroll
                for (int nf = 0; nf < 3; ++nf)
                    acc[4 + mf][nf] = __builtin_amdgcn_mfma_f32_16x16x32_bf16(a[mf], b[nf], acc[4 + mf][nf], 0, 0, 0);
            __builtin_amdgcn_s_setprio(0);
            // drain next tile's B + A-even (oldest 5 of 7 in flight)
            if (st) asm volatile("s_waitcnt vmcnt(2)\n\ts_barrier" ::: "memory");
            else    asm volatile("s_barrier" ::: "memory");
        }
    }

    // ---- epilogue: bias + scatter (q scaled for exp2 attention) ----
    const float QSCALE = 0.125f * 1.4426950408889634f;   // 1/8 * log2(e)
    #pragma unroll
    for (int nf = 0; nf < 3; ++nf) {
        const int n = n0 + wc * 48 + nf * 16 + l15;
        const int which = n >> 10;                        // wave-uniform
        const int nl = n & 1023, h = nl >> 6, d = nl & 63;
        const float bv = bias[n];
        #pragma unroll
        for (int mf = 0; mf < 8; ++mf) {
            const int mb = m0 + wr * 128 + mf * 16 + quad * 4;
            const int bb = mb >> 11, t0 = mb & 2047;
            f32x4 v4 = acc[mf][nf];
            if (which == 0) {
                size_t base = ((size_t)(bb * H_ + h) * T_ + t0) * HD_ + d;
                #pragma unroll
                for (int r = 0; r < 4; ++r)
                    q[base + (size_t)r * HD_] = f2bf((v4[r] + bv) * QSCALE);
            } else if (which == 1) {
                size_t base = ((size_t)(bb * H_ + h) * T_ + t0) * HD_ + d;
                #pragma unroll
                for (int r = 0; r < 4; ++r)
                    k[base + (size_t)r * HD_] = f2bf(v4[r] + bv);
            } else {
                uint2 o;
                o.x = cvt_pk_bf16(v4[0] + bv, v4[1] + bv);
                o.y = cvt_pk_bf16(v4[2] + bv, v4[3] + bv);
                *(uint2*)&vT[((size_t)(bb * H_ + h) * HD_ + d) * T_ + t0] = o;
            }
        }
    }
}

// ---------------------------------------------------------------------------
// Flash attention v7 = R8 work distribution + R9 LDS diet:
// one 64-row q-tile per block (1024 blocks, heavy first -> dynamic backfill,
// ALL 4 waves active every phase; 16.9k total block-phases).  LDS = K/V dbuf
// only (32 KB); P written into the DEAD half of Ks[cur] (K/V frags already in
// regs, enforced by mid lgkm+barrier).  2 barriers/phase.  S^T = K.Q^T,
// unnormalized exp2 (log2e folded into q upstream).
// ---------------------------------------------------------------------------
__global__ __launch_bounds__(256, 4)
void attn(const u16* __restrict__ q, const u16* __restrict__ k,
          const u16* __restrict__ vT, u16* __restrict__ y) {
    __shared__ __align__(16) u16 Ks[2 * 64 * 64];
    __shared__ __align__(16) u16 Vs[2 * 64 * 64];
    const int tid = threadIdx.x;
    const int lane = tid & 63, w = tid >> 6;
    const int l15 = lane & 15, quad = lane >> 4;
    const int srow = lane >> 3, schunk = (lane & 7) ^ srow;
    const int idx = blockIdx.x;
    const int bh = idx & 31;                        // bh%8 = XCD locality
    const int qt = 31 - (idx >> 5);                 // heavy first
    const u16* qp = q  + (size_t)bh * T_ * HD_;
    const u16* kp = k  + (size_t)bh * T_ * HD_;
    const u16* vp = vT + (size_t)bh * HD_ * T_;

    const int qrow = qt * 64 + w * 16 + l15;
    short8 qf[2];
    #pragma unroll
    for (int s = 0; s < 2; ++s)
        qf[s] = *(const short8*)&qp[(size_t)qrow * HD_ + s * 32 + quad * 8];

    auto stage = [&](int buf, int kt) {
        const int kb = kt * 64;
        // wave-local fence: previous phase's P reads (same rows, other buffer
        // half) must retire before the DMA write can be issued/hoisted here.
        asm volatile("s_waitcnt lgkmcnt(0)" ::: "memory");
        #pragma unroll
        for (int j = 0; j < 2; ++j) {
            int row = w * 16 + j * 8 + srow;
            __builtin_amdgcn_global_load_lds(
                (const AS1 void*)(kp + (size_t)(kb + row) * HD_ + schunk * 8),
                (AS3 void*)(Ks + buf * (64 * 64) + (w * 16 + j * 8) * 64), 16, 0, 0);
            __builtin_amdgcn_global_load_lds(
                (const AS1 void*)(vp + (size_t)row * T_ + kb + schunk * 8),
                (AS3 void*)(Vs + buf * (64 * 64) + (w * 16 + j * 8) * 64), 16, 0, 0);
        }
    };

    f32x4 o[4] = {};
    float l = 0.f;
    stage(0, 0);

    for (int kt = 0; kt <= qt; ++kt) {
        const int kb = kt * 64;
        const int cur = kt & 1;
        if (kt < qt) {
            stage(cur ^ 1, kt + 1);
            asm volatile("s_waitcnt vmcnt(4)\n\ts_barrier" ::: "memory");
        } else {
            asm volatile("s_waitcnt vmcnt(0)\n\ts_barrier" ::: "memory");
        }
        u16* Kc = Ks + cur * (64 * 64);
        const u16* Vc = Vs + cur * (64 * 64);

        short8 ka[4][2], va[4][2];
        #pragma unroll
        for (int ct = 0; ct < 4; ++ct)
            #pragma unroll
            for (int s = 0; s < 2; ++s) {
                int xo = ((s * 4 + quad) ^ (l15 & 7)) * 8;
                ka[ct][s] = *(const short8*)&Kc[(ct * 16 + l15) * 64 + xo];
                va[ct][s] = *(const short8*)&Vc[(ct * 16 + l15) * 64 + xo];
            }
        // all waves' K/V fragment reads complete before P overwrites Ks[cur]
        asm volatile("s_waitcnt lgkmcnt(0)\n\ts_barrier" ::: "memory");

        // S^T = K.Q^T  (C row = key, col = q = l15);  scores already *log2e
        f32x4 st[4] = {};
        #pragma unroll
        for (int s = 0; s < 2; ++s)
            #pragma unroll
            for (int ct = 0; ct < 4; ++ct)
                st[ct] = __builtin_amdgcn_mfma_f32_16x16x32_bf16(ka[ct][s], qf[s], st[ct], 0, 0, 0);

        float pe[16];
        #pragma unroll
        for (int ct = 0; ct < 4; ++ct)
            #pragma unroll
            for (int r = 0; r < 4; ++r)
                pe[ct * 4 + r] = exp2f(st[ct][r]);
        if (kt == qt) {                              // wave-uniform causal mask
            #pragma unroll
            for (int ct = 0; ct < 4; ++ct)
                #pragma unroll
                for (int r = 0; r < 4; ++r)
                    if ((kb + ct * 16 + quad * 4 + r) > qrow) pe[ct * 4 + r] = 0.f;
        }
        float psum = 0.f;
        #pragma unroll
        for (int i = 0; i < 16; ++i) psum += pe[i];
        l += psum;

        // P -> dead Ks[cur], wave-own rows w*16.., stride 64, XOR chunks
        u16* Pw = Kc + (w * 16 + l15) * 64;
        #pragma unroll
        for (int ct = 0; ct < 4; ++ct) {
            int chunk = ct * 2 + (quad >> 1);
            int off = ((chunk ^ (l15 & 7)) << 3) + (quad & 1) * 4;
            uint2 pk;
            pk.x = cvt_pk_bf16(pe[ct * 4 + 0], pe[ct * 4 + 1]);
            pk.y = cvt_pk_bf16(pe[ct * 4 + 2], pe[ct * 4 + 3]);
            *(uint2*)&Pw[off] = pk;
        }
        asm volatile("s_waitcnt lgkmcnt(0)" ::: "memory");   // wave-local RT

        // O^T = V^T . P^T
        #pragma unroll
        for (int s = 0; s < 2; ++s) {
            short8 pb = *(const short8*)&Pw[(((s * 4 + quad) ^ (l15 & 7)) << 3)];
            #pragma unroll
            for (int n = 0; n < 4; ++n)
                o[n] = __builtin_amdgcn_mfma_f32_16x16x32_bf16(va[n][s], pb, o[n], 0, 0, 0);
        }
        // no end barrier: P rows are wave-private; cross-wave safety is the
        // mid lgkm+barrier, buffer reuse safety is the top vmcnt+barrier.
    }

    l += __shfl_xor(l, 16); l += __shfl_xor(l, 32);
    const float inv = 1.f / l;
    const int bb = bh >> 4, h = bh & 15;
    #pragma unroll
    for (int n = 0; n < 4; ++n) {
        uint2 pk;
        pk.x = cvt_pk_bf16(o[n][0] * inv, o[n][1] * inv);
        pk.y = cvt_pk_bf16(o[n][2] * inv, o[n][3] * inv);
        *(uint2*)&y[((size_t)(bb * T_ + qrow)) * C_ + h * 64 + n * 16 + quad * 4] = pk;
    }
}

// ---------------------------------------------------------------------------
// Output projection: y[4096][1024] @ WprojT[1024][1024]^T + bias -> fp32 out.
// 128x64 tile (512 blocks, 48 KB LDS -> 3 blocks/CU).
// ---------------------------------------------------------------------------
__global__ __launch_bounds__(256, 3)
void proj_gemm(const u16* __restrict__ A, const u16* __restrict__ BT,
               const float* __restrict__ bias, float* __restrict__ out) {
    __shared__ __align__(16) u16 As[2 * 128 * 64];
    __shared__ __align__(16) u16 Bs[2 * 64 * 64];
    const int m0 = blockIdx.y * 128, n0 = blockIdx.x * 64;
    const int tid = threadIdx.x;
    const int lane = tid & 63, w = tid >> 6;
    const int l15 = lane & 15, quad = lane >> 4;
    const int row0 = (w & 1) * 64, col0 = (w >> 1) * 32;
    const int srow = lane >> 3;
    const int schunk = (lane & 7) ^ srow;
    f32x4 acc[4][2] = {};

    auto stage = [&](int buf, int k0) {
        #pragma unroll
        for (int j = 0; j < 4; ++j) {
            int rbase = w * 32 + j * 8;
            const u16* ga = A + (size_t)(m0 + rbase + srow) * 1024 + k0 + schunk * 8;
            __builtin_amdgcn_global_load_lds((const AS1 void*)ga,
                (AS3 void*)(As + buf * (128 * 64) + rbase * 64), 16, 0, 0);
        }
        #pragma unroll
        for (int j = 0; j < 2; ++j) {
            int rbase = w * 16 + j * 8;
            const u16* gb = BT + (size_t)(n0 + rbase + srow) * 1024 + k0 + schunk * 8;
            __builtin_amdgcn_global_load_lds((const AS1 void*)gb,
                (AS3 void*)(Bs + buf * (64 * 64) + rbase * 64), 16, 0, 0);
        }
    };

    stage(0, 0);
    #pragma unroll
    for (int it = 0; it < 16; ++it) {
        const int cur = it & 1;
        if (it + 1 < 16) {
            stage(cur ^ 1, (it + 1) * 64);
            asm volatile("s_waitcnt vmcnt(6)\n\ts_barrier" ::: "memory");
        } else {
            asm volatile("s_waitcnt vmcnt(0)\n\ts_barrier" ::: "memory");
        }
        const u16* Ac = As + cur * (128 * 64);
        const u16* Bc = Bs + cur * (64 * 64);
        #pragma unroll
        for (int s = 0; s < 2; ++s) {
            short8 a[4], b[2];
            #pragma unroll
            for (int rt = 0; rt < 4; ++rt) {
                int row = row0 + rt * 16 + l15;
                a[rt] = *(const short8*)&Ac[row * 64 + (((s * 4 + quad) ^ (l15 & 7)) * 8)];
            }
            #pragma unroll
            for (int ct = 0; ct < 2; ++ct) {
                int row = col0 + ct * 16 + l15;
                b[ct] = *(const short8*)&Bc[row * 64 + (((s * 4 + quad) ^ (l15 & 7)) * 8)];
            }
            #pragma unroll
            for (int rt = 0; rt < 4; ++rt)
                #pragma unroll
                for (int ct = 0; ct < 2; ++ct)
                    acc[rt][ct] = __builtin_amdgcn_mfma_f32_16x16x32_bf16(a[rt], b[ct], acc[rt][ct], 0, 0, 0);
        }
        asm volatile("s_waitcnt lgkmcnt(0)\n\ts_barrier" ::: "memory");
    }

    #pragma unroll
    for (int ct = 0; ct < 2; ++ct) {
        int n = n0 + col0 + ct * 16 + l15;
        float bv = bias[n];
        #pragma unroll
        for (int rt = 0; rt < 4; ++rt) {
            int mb = m0 + row0 + rt * 16 + quad * 4;
            f32x4 v4 = acc[rt][ct];
            #pragma unroll
            for (int r = 0; r < 4; ++r)
                out[(size_t)(mb + r) * 1024 + n] = v4[r] + bv;
        }
    }
}

// ---------------------------------------------------------------------------
extern "C" void kernel_launch(void* const* d_in, const int* in_sizes, int n_in,
                              void* d_out, int out_size, void* d_ws, size_t ws_size,
                              hipStream_t stream) {
    const float* x     = (const float*)d_in[0];
    const float* Wqkv  = (const float*)d_in[1];
    const float* bqkv  = (const float*)d_in[2];
    const float* Wproj = (const float*)d_in[3];
    const float* bproj = (const float*)d_in[4];

    u16* xb     = (u16*)d_ws;
    u16* WqkvT  = xb + (size_t)4 * 1024 * 1024;
    u16* WprojT = WqkvT + (size_t)3 * 1024 * 1024;
    u16* q      = WprojT + (size_t)1024 * 1024;
    u16* kk     = q + (size_t)4 * 1024 * 1024;
    u16* vT     = kk + (size_t)4 * 1024 * 1024;
    u16* y      = vT + (size_t)4 * 1024 * 1024;

    conv_all<<<5120, 256, 0, stream>>>(x, xb, Wqkv, WqkvT, Wproj, WprojT);
    qkv_gemm<<<256, 512, 0, stream>>>(xb, WqkvT, bqkv, q, kk, vT);
    attn<<<1024, 256, 0, stream>>>(q, kk, vT, y);
    proj_gemm<<<dim3(C_ / 64, BT_ / 128), 256, 0, stream>>>(y, WprojT, bproj, (float*)d_out);
}